// Round 1
// baseline (18341.917 us; speedup 1.0000x reference)
//
#include <hip/hip_runtime.h>

// Encoder: 3-layer bidirectional-weights LSTM (both dirs scan forward per the
// reference), H=256, B=64, T=1024, then 256->81 linear + argmax (softmax is
// monotone -> dead code).
//
// R6b: R5 (LLC-coherent h exchange via fused issue+wait asm helpers, fence-free
// relaxed barrier) + ALL weights staged once into LDS ([k4][8rows][4], 59 KB):
// weight reads become wave-uniform ds_read_b128 broadcasts (lgkm pipe) and the
// per-k4 weight address VALU (~6.4us/tick in R5) disappears. FMA order
// bit-identical to R4/R5 (ascending k4, same chains, bias-first epilogue).
// (R6's split issue/wait asm with tied float4 operands doesn't compile: LLVM
// "tied indirect register inputs" -- fused helpers retained instead.)
//
// R7: resubmission of R6b unchanged — previous round's bench was an MI355X
// container infra failure (no counters, no timing). Re-establish baseline.

#define H_ 256
#define B_ 64
#define T_ 1024
#define NBLK 256
#define NTHR 1024
#define HBUF 98304     // floats per h ring buffer: 6 cells * 16384
#define NTICK 1026

// ws byte offsets
#define OFF_GEN  0
#define OFF_ROOT 64
#define OFF_CNT  128          // 8 counters, 64B apart
#define OFF_H    4096         // hbuf[2][6][16384] floats = 786432 B
#define OFF_XT   1048576      // xT2[1024][16][64][4] floats = 16 MB
#define OFF_YS   17825792     // ys[1024][64][256] floats = 64 MB

__device__ __forceinline__ float sigf(float x) {
  return 1.0f / (1.0f + __expf(-x));
}
__device__ __forceinline__ float tanhf_(float x) {
  float e = __expf(-2.0f * fabsf(x));
  float r = (1.0f - e) / (1.0f + e);
  return x >= 0.0f ? r : -r;
}

// ---- LLC-coherent (bypass L1/L2) access helpers (R5-proven) ----
__device__ __forceinline__ void llc_ld1(const float4* p, float4& r) {
  asm volatile(
      "global_load_dwordx4 %0, %1, off sc0 sc1\n\t"
      "s_waitcnt vmcnt(0)"
      : "=v"(r)
      : "v"(p)
      : "memory");
}
// 4 consecutive k4 rows (1024 B apart), one drain: 4-deep MLP
__device__ __forceinline__ void llc_ld4(const float4* p, float4& r0, float4& r1,
                                        float4& r2, float4& r3) {
  asm volatile(
      "global_load_dwordx4 %0, %4, off sc0 sc1\n\t"
      "global_load_dwordx4 %1, %4, off offset:1024 sc0 sc1\n\t"
      "global_load_dwordx4 %2, %4, off offset:2048 sc0 sc1\n\t"
      "global_load_dwordx4 %3, %4, off offset:3072 sc0 sc1\n\t"
      "s_waitcnt vmcnt(0)"
      : "=&v"(r0), "=&v"(r1), "=&v"(r2), "=&v"(r3)
      : "v"(p)
      : "memory");
}
__device__ __forceinline__ void llc_st1(float* p, float v) {
  asm volatile(
      "global_store_dword %0, %1, off sc0 sc1\n\t"
      "s_waitcnt vmcnt(0)" ::"v"(p),
      "v"(v)
      : "memory");
}
__device__ __forceinline__ void llc_st2(float* p1, float v1, float* p2, float v2) {
  asm volatile(
      "global_store_dword %0, %1, off sc0 sc1\n\t"
      "global_store_dword %2, %3, off sc0 sc1\n\t"
      "s_waitcnt vmcnt(0)" ::"v"(p1),
      "v"(v1), "v"(p2), "v"(v2)
      : "memory");
}

// ---------------- x transpose: x[b][k][t] -> xT2[t][k>>2][b][k&3] ----------------
__global__ __launch_bounds__(64) void transpose_x(const float* __restrict__ x,
                                                  float* __restrict__ xT) {
  __shared__ float tile[64][65];
  const int k = blockIdx.y;
  const int t0 = blockIdx.x * 64;
  const int lane = threadIdx.x;
  for (int bi = 0; bi < 64; ++bi)
    tile[bi][lane] = x[bi * 65536 + k * 1024 + t0 + lane];
  __syncthreads();
  for (int ti = 0; ti < 64; ++ti)
    xT[(size_t)(t0 + ti) * 4096 + (k >> 2) * 256 + lane * 4 + (k & 3)] =
        tile[lane][ti];
}

// ---------------- 8-row FMA body for one k4 (order matches R4/R5 bitwise) ----
// weights from LDS: wl[k4*32 + a*4 .. +3]  (wave-uniform ds_read_b128 broadcast)
__device__ __forceinline__ void body8(float* __restrict__ acc, const float4 av,
                                      const float* __restrict__ wl,
                                      const int k4) {
  const float* wp = wl + (size_t)k4 * 32;
#pragma unroll
  for (int a = 0; a < 8; ++a) {
    float4 wq = *(const float4*)(wp + a * 4);
    acc[a] += wq.x * av.x + wq.y * av.y + wq.z * av.z + wq.w * av.w;
  }
}

// segment driver: k4 ascending, batches of 4 then tail (same fp order as R4/R5)
// k4 is task-global; act indexed by (k4 - actOff); weights by task-global k4.
__device__ __forceinline__ void seg8(float* __restrict__ acc, const int a,
                                     const int b, const float4* __restrict__ act,
                                     const int actOff,
                                     const float* __restrict__ wl,
                                     const int lane, const bool byp) {
  int k4 = a;
  for (; k4 + 4 <= b; k4 += 4) {
    const float4* p = act + (size_t)(k4 - actOff) * 64 + lane;
    float4 v0, v1, v2, v3;
    if (byp) {
      llc_ld4(p, v0, v1, v2, v3);
    } else {
      v0 = p[0];
      v1 = p[64];
      v2 = p[128];
      v3 = p[192];
    }
    body8(acc, v0, wl, k4 + 0);
    body8(acc, v1, wl, k4 + 1);
    body8(acc, v2, wl, k4 + 2);
    body8(acc, v3, wl, k4 + 3);
  }
  for (; k4 < b; ++k4) {
    const float4* p = act + (size_t)(k4 - actOff) * 64 + lane;
    float4 v;
    if (byp)
      llc_ld1(p, v);
    else
      v = *p;
    body8(acc, v, wl, k4);
  }
}

// ---------------- one gate task: 8 rows (2 units x 4 gates), K4 k4-groups ----
__device__ __forceinline__ void task8(
    const int w, const int lane, const int tid, const int u0,
    const int K4, const int nA4,
    const float4* __restrict__ actA, const bool bypA,  // k4 in [0, nA4)
    const float4* __restrict__ actB, const bool bypB,  // k4 in [nA4, K4)
    const float* __restrict__ wl,      // LDS weight base for this task
    const float* __restrict__ bias,    // bias[g*256 + u]
    float* __restrict__ cst2,          // LDS [2][64]
    float* __restrict__ hcell,         // h write base for this cell (LLC)
    float* __restrict__ ysrow,         // ys + t*16384 or nullptr (LLC)
    float (*red)[64][12], const bool lastTask) {
  const int slice = K4 >> 4;           // K4/16 waves
  const int lo = w * slice, hi = lo + slice;
  float acc[8] = {0.f, 0.f, 0.f, 0.f, 0.f, 0.f, 0.f, 0.f};

  // segment A: k4 in [lo, min(hi,nA4))
  {
    const int b4 = hi < nA4 ? hi : nA4;
    if (lo < b4) seg8(acc, lo, b4, actA, 0, wl, lane, bypA);
  }
  // segment B: k4 in [max(lo,nA4), hi)
  {
    const int a4 = lo > nA4 ? lo : nA4;
    if (a4 < hi) seg8(acc, a4, hi, actB, nA4, wl, lane, bypB);
  }

  // 8 partials -> 2x b128 LDS writes
  *(float4*)&red[w][lane][0] = make_float4(acc[0], acc[1], acc[2], acc[3]);
  *(float4*)&red[w][lane][4] = make_float4(acc[4], acc[5], acc[6], acc[7]);
  __syncthreads();

  if (tid < 128) {
    const int uu = tid >> 6, b = tid & 63;
    // bias FIRST, then wave partials ascending (bit-identical to R2/R4/R5)
    float gi = bias[0 * 256 + u0 + uu];
    float gf = bias[1 * 256 + u0 + uu];
    float gg = bias[2 * 256 + u0 + uu];
    float go = bias[3 * 256 + u0 + uu];
#pragma unroll
    for (int ww = 0; ww < 16; ++ww) {
      float4 s = *(const float4*)&red[ww][b][uu * 4];
      gi += s.x; gf += s.y; gg += s.z; go += s.w;
    }
    float iv = sigf(gi), fv = sigf(gf), gv = tanhf_(gg), ov = sigf(go);
    float c = fv * cst2[uu * 64 + b] + iv * gv;
    cst2[uu * 64 + b] = c;
    float h = ov * tanhf_(c);
    const int u = u0 + uu;
    float* hp = hcell + (u >> 2) * 256 + b * 4 + (u & 3);
    if (ysrow)
      llc_st2(hp, h, ysrow + b * 256 + u, h);
    else
      llc_st1(hp, h);
  }
  if (!lastTask) __syncthreads();
}

// ---------------- persistent skewed LSTM ----------------
__global__ __launch_bounds__(NTHR, 1) void lstm_persistent(
    const float* __restrict__ Wih0, const float* __restrict__ Whh0,
    const float* __restrict__ b0, const float* __restrict__ Wih12,
    const float* __restrict__ Whh12, const float* __restrict__ b12, char* wsb) {
  unsigned* gen = (unsigned*)(wsb + OFF_GEN);
  unsigned* root = (unsigned*)(wsb + OFF_ROOT);
  float* hb = (float*)(wsb + OFF_H);
  const float* xT = (const float*)(wsb + OFF_XT);
  float* ys = (float*)(wsb + OFF_YS);

  __shared__ float red[16][64][12];   // 48 KB
  __shared__ float cst[3][2][64];     // per-layer c state (1.5 KB)
  __shared__ float wlds[14848];       // 59 KB: per-task [k4][8 rows][4]

  const int bid = blockIdx.x;
  const int tid = threadIdx.x;
  const int lane = tid & 63;
  const int w = __builtin_amdgcn_readfirstlane(tid >> 6);  // uniform wave id
  const int d = bid >> 7;          // direction 0/1
  const int u0 = (bid & 127) * 2;  // unit tile base

  if (tid < 384) ((float*)cst)[tid] = 0.f;

  // ---- stage all weights for this block into LDS (once) ----
  auto stage = [&](const float* wA, int wAs, const float* wB, int wBs,
                   int K4s, int NA4s, float* dst) {
    const int nq = K4s * 8;
    for (int idx = tid; idx < nq; idx += NTHR) {
      const int a = idx / K4s;
      const int k4 = idx - a * K4s;
      const int row = (a & 3) * 256 + u0 + (a >> 2);
      const float* src = (k4 < NA4s) ? (wA + (size_t)row * wAs + k4 * 4)
                                     : (wB + (size_t)row * wBs + (k4 - NA4s) * 4);
      float4 q = *(const float4*)src;
      *(float4*)(dst + ((size_t)k4 * 8 + a) * 4) = q;
    }
  };
  stage(Wih0 + (size_t)d * 65536, 64, Whh0 + (size_t)d * 262144, 256, 80, 16,
        wlds);
  stage(Wih12 + (size_t)d * 524288, 512, Whh12 + (size_t)d * 262144, 256, 192,
        128, wlds + 2560);
  stage(Wih12 + (size_t)(2 + d) * 524288, 512,
        Whh12 + (size_t)(2 + d) * 262144, 256, 192, 128, wlds + 8704);
  __syncthreads();

  unsigned* mycnt = (unsigned*)(wsb + OFF_CNT + (size_t)(bid & 7) * 64);

  for (unsigned tick = 0; tick < NTICK; ++tick) {
    const float* R = hb + ((tick + 1) & 1) * HBUF;  // produced last tick
    float* W = hb + (tick & 1) * HBUF;              // produced this tick
    const float4* Rf4 = (const float4*)R;

    const bool has0 = tick < 1024;
    const bool has1 = tick >= 1 && tick < 1025;
    const bool has2 = tick >= 2;

    // Layer 0 (cell d): t = tick; K4 = 16 (x, cached) + 64 (rec h, LLC)
    if (has0) {
      task8(w, lane, tid, u0, 80, 16,
            (const float4*)xT + (size_t)tick * 1024, false,
            Rf4 + (size_t)d * 4096, true,
            wlds, b0 + d * 1024, &cst[0][0][0],
            W + (size_t)d * 16384, nullptr, red, !(has1 || has2));
    }
    // Layer 1 (cell 2+d): t = tick-1; K4 = 128 (cells 0,1) + 64 (rec)
    if (has1) {
      task8(w, lane, tid, u0, 192, 128,
            Rf4, true,
            Rf4 + (size_t)(2 + d) * 4096, true,
            wlds + 2560, b12 + d * 1024, &cst[1][0][0],
            W + (size_t)(2 + d) * 16384, nullptr, red, !has2);
    }
    // Layer 2 (cell 4+d): t = tick-2; K4 = 128 (cells 2,3) + 64 (rec)
    if (has2) {
      const int t = (int)tick - 2;
      task8(w, lane, tid, u0, 192, 128,
            Rf4 + (size_t)2 * 4096, true,
            Rf4 + (size_t)(4 + d) * 4096, true,
            wlds + 8704, b12 + (2 + d) * 1024, &cst[2][0][0],
            W + (size_t)(4 + d) * 16384,
            (d == 1) ? (ys + (size_t)t * 16384) : nullptr, red, true);
    }

    // -------- grid barrier: pure relaxed LLC atomics, NO fences --------
    __syncthreads();
    if (tid == 0) {
      unsigned old = __hip_atomic_fetch_add(mycnt, 1u, __ATOMIC_RELAXED,
                                            __HIP_MEMORY_SCOPE_AGENT);
      if (old == (tick + 1) * (NBLK / 8) - 1) {
        unsigned r = __hip_atomic_fetch_add(root, 1u, __ATOMIC_RELAXED,
                                            __HIP_MEMORY_SCOPE_AGENT);
        if (r == (tick + 1) * 8 - 1) {
          __hip_atomic_store(gen, tick + 1, __ATOMIC_RELAXED,
                             __HIP_MEMORY_SCOPE_AGENT);
        }
      }
      while (__hip_atomic_load(gen, __ATOMIC_RELAXED, __HIP_MEMORY_SCOPE_AGENT) <
             tick + 1) {
        __builtin_amdgcn_s_sleep(2);
      }
    }
    __syncthreads();
  }
}

// ---------------- conv(256->81) + argmax ----------------
__global__ __launch_bounds__(256) void conv_argmax(const float* __restrict__ yst,
                                                   const float* __restrict__ cw,
                                                   const float* __restrict__ cb,
                                                   int* __restrict__ out) {
  const int t = blockIdx.x;
  const int tid = threadIdx.x, lane = tid & 63, w = tid >> 6;
  const float* yrow = yst + (size_t)t * (B_ * H_) + lane * H_;
  float best = -3.4e38f;
  int bi = 0;
  for (int og = 0; og < 3; ++og) {
    float acc[8];
    int ov[8];
#pragma unroll
    for (int m = 0; m < 8; ++m) {
      int o = w + 32 * og + 4 * m;
      ov[m] = (o < 81) ? o : 80;
      acc[m] = (o < 81) ? cb[o] : -3.4e38f;
    }
    for (int uu = 0; uu < H_; uu += 4) {
      float4 y4 = *(const float4*)(yrow + uu);
#pragma unroll
      for (int m = 0; m < 8; ++m) {
        const float* wr = cw + ov[m] * H_ + uu;
        acc[m] += wr[0] * y4.x + wr[1] * y4.y + wr[2] * y4.z + wr[3] * y4.w;
      }
    }
#pragma unroll
    for (int m = 0; m < 8; ++m) {
      int o = w + 32 * og + 4 * m;
      if (o < 81 && acc[m] > best) {
        best = acc[m];
        bi = o;
      }
    }
  }
  __shared__ float sv[4][64];
  __shared__ int si[4][64];
  sv[w][lane] = best;
  si[w][lane] = bi;
  __syncthreads();
  if (tid < 64) {
    float bv = sv[0][tid];
    int bo = si[0][tid];
#pragma unroll
    for (int ww = 1; ww < 4; ++ww) {
      float v = sv[ww][tid];
      int o = si[ww][tid];
      if (v > bv || (v == bv && o < bo)) {
        bv = v;
        bo = o;
      }
    }
    out[tid * T_ + t] = bo;
  }
}

extern "C" void kernel_launch(void* const* d_in, const int* in_sizes, int n_in,
                              void* d_out, int out_size, void* d_ws,
                              size_t ws_size, hipStream_t stream) {
  const float* x = (const float*)d_in[0];
  const float* Wih0 = (const float*)d_in[1];
  const float* Whh0 = (const float*)d_in[2];
  const float* b0 = (const float*)d_in[3];
  const float* Wih12 = (const float*)d_in[4];
  const float* Whh12 = (const float*)d_in[5];
  const float* b12 = (const float*)d_in[6];
  const float* cw = (const float*)d_in[7];
  const float* cb = (const float*)d_in[8];
  int* out = (int*)d_out;
  char* wsb = (char*)d_ws;

  // zero flags + h ring (ws is re-poisoned 0xAA before every launch)
  hipMemsetAsync(wsb, 0, OFF_H + 786432, stream);
  transpose_x<<<dim3(16, 64, 1), dim3(64, 1, 1), 0, stream>>>(
      x, (float*)(wsb + OFF_XT));
  lstm_persistent<<<dim3(NBLK, 1, 1), dim3(NTHR, 1, 1), 0, stream>>>(
      Wih0, Whh0, b0, Wih12, Whh12, b12, wsb);
  conv_argmax<<<dim3(T_, 1, 1), dim3(256, 1, 1), 0, stream>>>(
      (const float*)(wsb + OFF_YS), cw, cb, out);
}

// Round 2
// 16165.857 us; speedup vs baseline: 1.1346x; 1.1346x over previous
//
#include <hip/hip_runtime.h>

// Encoder: 3-layer bidirectional-weights LSTM (both dirs scan forward per the
// reference), H=256, B=64, T=1024, then 256->81 linear + argmax (softmax is
// monotone -> dead code).
//
// R8: task-parallel restructure of R6b.
//  - Waves partitioned across the 3 per-tick tasks (they are independent:
//    L1/L2 read LAST tick's h): waves 0-3 = L0 (20 k4), 4-9 = L1 (32 k4),
//    10-15 = L2 (32 k4). One K-phase + ONE fused epilogue per tick instead of
//    3 sequential task phases (6 syncthreads -> 2).
//  - Fused 192-thread epilogue (3 cells in parallel), per-cell reduction over
//    4/6 waves (not 16), biases pre-staged in LDS, paired-unit float2 h-store
//    (u0 even -> u0,u0+1 adjacent in [u>>2][b][u&3] layout), ONE vmcnt(0)
//    drain for all stores; ys store is a plain cached store (kernel-boundary
//    visibility suffices for conv_argmax).
//  - llc_ld8 (two addr regs; global offset is 13-bit signed so max 4095B per
//    addr): halves LLC drain count on the h path (4 per L1/L2 wave per tick).
// FP summation grouping changes vs R6b (per-task wave counts 4/6/6). Safe:
// output is int argmax; absmax was 0.0 with an order already unrelated to the
// JAX reference, so reorder-scale (~1e-6) perturbations don't flip argmax.

#define H_ 256
#define B_ 64
#define T_ 1024
#define NBLK 256
#define NTHR 1024
#define HBUF 98304     // floats per h ring buffer: 6 cells * 16384
#define NTICK 1026

// ws byte offsets
#define OFF_GEN  0
#define OFF_ROOT 64
#define OFF_CNT  128          // 8 counters, 64B apart
#define OFF_H    4096         // hbuf[2][6][16384] floats = 786432 B
#define OFF_XT   1048576      // xT2[1024][16][64][4] floats = 16 MB
#define OFF_YS   17825792     // ys[1024][64][256] floats = 64 MB

__device__ __forceinline__ float sigf(float x) {
  return 1.0f / (1.0f + __expf(-x));
}
__device__ __forceinline__ float tanhf_(float x) {
  float e = __expf(-2.0f * fabsf(x));
  float r = (1.0f - e) / (1.0f + e);
  return x >= 0.0f ? r : -r;
}

// ---- LLC-coherent (bypass L1/L2) access helpers ----
__device__ __forceinline__ void llc_ld1(const float4* p, float4& r) {
  asm volatile(
      "global_load_dwordx4 %0, %1, off sc0 sc1\n\t"
      "s_waitcnt vmcnt(0)"
      : "=v"(r)
      : "v"(p)
      : "memory");
}
__device__ __forceinline__ void llc_ld4(const float4* p, float4& r0, float4& r1,
                                        float4& r2, float4& r3) {
  asm volatile(
      "global_load_dwordx4 %0, %4, off sc0 sc1\n\t"
      "global_load_dwordx4 %1, %4, off offset:1024 sc0 sc1\n\t"
      "global_load_dwordx4 %2, %4, off offset:2048 sc0 sc1\n\t"
      "global_load_dwordx4 %3, %4, off offset:3072 sc0 sc1\n\t"
      "s_waitcnt vmcnt(0)"
      : "=&v"(r0), "=&v"(r1), "=&v"(r2), "=&v"(r3)
      : "v"(p)
      : "memory");
}
// 8 consecutive k4 rows, one drain. Two address regs (13-bit signed offset cap).
__device__ __forceinline__ void llc_ld8(const float4* p, const float4* q,
                                        float4& r0, float4& r1, float4& r2,
                                        float4& r3, float4& r4, float4& r5,
                                        float4& r6, float4& r7) {
  asm volatile(
      "global_load_dwordx4 %0, %8, off sc0 sc1\n\t"
      "global_load_dwordx4 %1, %8, off offset:1024 sc0 sc1\n\t"
      "global_load_dwordx4 %2, %8, off offset:2048 sc0 sc1\n\t"
      "global_load_dwordx4 %3, %8, off offset:3072 sc0 sc1\n\t"
      "global_load_dwordx4 %4, %9, off sc0 sc1\n\t"
      "global_load_dwordx4 %5, %9, off offset:1024 sc0 sc1\n\t"
      "global_load_dwordx4 %6, %9, off offset:2048 sc0 sc1\n\t"
      "global_load_dwordx4 %7, %9, off offset:3072 sc0 sc1\n\t"
      "s_waitcnt vmcnt(0)"
      : "=&v"(r0), "=&v"(r1), "=&v"(r2), "=&v"(r3), "=&v"(r4), "=&v"(r5),
        "=&v"(r6), "=&v"(r7)
      : "v"(p), "v"(q)
      : "memory");
}
// paired h store (8B), NO drain -- one shared vmcnt(0) before the barrier
__device__ __forceinline__ void llc_st_f2(float* p, float2 v) {
  asm volatile("global_store_dwordx2 %0, %1, off sc0 sc1" ::"v"(p), "v"(v)
               : "memory");
}

// ---------------- x transpose: x[b][k][t] -> xT2[t][k>>2][b][k&3] ----------------
__global__ __launch_bounds__(64) void transpose_x(const float* __restrict__ x,
                                                  float* __restrict__ xT) {
  __shared__ float tile[64][65];
  const int k = blockIdx.y;
  const int t0 = blockIdx.x * 64;
  const int lane = threadIdx.x;
  for (int bi = 0; bi < 64; ++bi)
    tile[bi][lane] = x[bi * 65536 + k * 1024 + t0 + lane];
  __syncthreads();
  for (int ti = 0; ti < 64; ++ti)
    xT[(size_t)(t0 + ti) * 4096 + (k >> 2) * 256 + lane * 4 + (k & 3)] =
        tile[lane][ti];
}

// ---------------- 8-row FMA body for one k4 ----
// weights from LDS: wl[k4*32 + a*4 .. +3]  (wave-uniform ds_read_b128 broadcast)
__device__ __forceinline__ void body8(float* __restrict__ acc, const float4 av,
                                      const float* __restrict__ wl,
                                      const int k4) {
  const float* wp = wl + (size_t)k4 * 32;
#pragma unroll
  for (int a = 0; a < 8; ++a) {
    float4 wq = *(const float4*)(wp + a * 4);
    acc[a] += wq.x * av.x + wq.y * av.y + wq.z * av.z + wq.w * av.w;
  }
}

// LLC-path K runner: n k4-groups from bufbase starting at buffer k4 `bufk4`,
// weight index starting at task-global `wk4`. Batches of 8 / 4 / 1.
__device__ __forceinline__ void runLLC(float* __restrict__ acc,
                                       const float4* __restrict__ bufbase,
                                       const int bufk4, const int wk4,
                                       const int n,
                                       const float* __restrict__ wl,
                                       const int lane) {
  const float4* p = bufbase + (size_t)bufk4 * 64 + lane;
  int k = 0;
  for (; k + 8 <= n; k += 8) {
    float4 v0, v1, v2, v3, v4, v5, v6, v7;
    llc_ld8(p, p + 256, v0, v1, v2, v3, v4, v5, v6, v7);
    p += 512;
    body8(acc, v0, wl, wk4 + k + 0);
    body8(acc, v1, wl, wk4 + k + 1);
    body8(acc, v2, wl, wk4 + k + 2);
    body8(acc, v3, wl, wk4 + k + 3);
    body8(acc, v4, wl, wk4 + k + 4);
    body8(acc, v5, wl, wk4 + k + 5);
    body8(acc, v6, wl, wk4 + k + 6);
    body8(acc, v7, wl, wk4 + k + 7);
  }
  for (; k + 4 <= n; k += 4) {
    float4 v0, v1, v2, v3;
    llc_ld4(p, v0, v1, v2, v3);
    p += 256;
    body8(acc, v0, wl, wk4 + k + 0);
    body8(acc, v1, wl, wk4 + k + 1);
    body8(acc, v2, wl, wk4 + k + 2);
    body8(acc, v3, wl, wk4 + k + 3);
  }
  for (; k < n; ++k) {
    float4 v;
    llc_ld1(p, v);
    p += 64;
    body8(acc, v, wl, wk4 + k);
  }
}

// cached-path K runner (xT: written by earlier kernel, plain loads ok)
__device__ __forceinline__ void runCached(float* __restrict__ acc,
                                          const float4* __restrict__ bufbase,
                                          const int bufk4, const int wk4,
                                          const int n,
                                          const float* __restrict__ wl,
                                          const int lane) {
  const float4* p = bufbase + (size_t)bufk4 * 64 + lane;
  int k = 0;
  for (; k + 4 <= n; k += 4) {
    float4 v0 = p[0], v1 = p[64], v2 = p[128], v3 = p[192];
    p += 256;
    body8(acc, v0, wl, wk4 + k + 0);
    body8(acc, v1, wl, wk4 + k + 1);
    body8(acc, v2, wl, wk4 + k + 2);
    body8(acc, v3, wl, wk4 + k + 3);
  }
  for (; k < n; ++k) {
    float4 v = *p;
    p += 64;
    body8(acc, v, wl, wk4 + k);
  }
}

// ---------------- persistent skewed LSTM ----------------
__global__ __launch_bounds__(NTHR, 1) void lstm_persistent(
    const float* __restrict__ Wih0, const float* __restrict__ Whh0,
    const float* __restrict__ b0, const float* __restrict__ Wih12,
    const float* __restrict__ Whh12, const float* __restrict__ b12, char* wsb) {
  unsigned* gen = (unsigned*)(wsb + OFF_GEN);
  unsigned* root = (unsigned*)(wsb + OFF_ROOT);
  float* hb = (float*)(wsb + OFF_H);
  const float* xT = (const float*)(wsb + OFF_XT);
  float* ys = (float*)(wsb + OFF_YS);

  __shared__ float red[16][64][12];   // 48 KB
  __shared__ float cst[3][2][64];     // per-layer c state (1.5 KB)
  __shared__ float wlds[14848];       // 59 KB: per-task [k4][8 rows][4]
  __shared__ float blds[3][8];        // biases: [cell][a] matching acc order

  const int bid = blockIdx.x;
  const int tid = threadIdx.x;
  const int lane = tid & 63;
  const int w = __builtin_amdgcn_readfirstlane(tid >> 6);  // uniform wave id
  const int d = bid >> 7;          // direction 0/1
  const int u0 = (bid & 127) * 2;  // unit tile base (even)

  if (tid < 384) ((float*)cst)[tid] = 0.f;

  // ---- stage all weights for this block into LDS (once) ----
  auto stage = [&](const float* wA, int wAs, const float* wB, int wBs,
                   int K4s, int NA4s, float* dst) {
    const int nq = K4s * 8;
    for (int idx = tid; idx < nq; idx += NTHR) {
      const int a = idx / K4s;
      const int k4 = idx - a * K4s;
      const int row = (a & 3) * 256 + u0 + (a >> 2);
      const float* src = (k4 < NA4s) ? (wA + (size_t)row * wAs + k4 * 4)
                                     : (wB + (size_t)row * wBs + (k4 - NA4s) * 4);
      float4 q = *(const float4*)src;
      *(float4*)(dst + ((size_t)k4 * 8 + a) * 4) = q;
    }
  };
  stage(Wih0 + (size_t)d * 65536, 64, Whh0 + (size_t)d * 262144, 256, 80, 16,
        wlds);
  stage(Wih12 + (size_t)d * 524288, 512, Whh12 + (size_t)d * 262144, 256, 192,
        128, wlds + 2560);
  stage(Wih12 + (size_t)(2 + d) * 524288, 512,
        Whh12 + (size_t)(2 + d) * 262144, 256, 192, 128, wlds + 8704);
  // biases: blds[cell][a] = bias_cell[(a&3)*256 + u0 + (a>>2)]
  if (tid < 24) {
    const int cell = tid >> 3, a = tid & 7;
    const float* bb = (cell == 0) ? (b0 + d * 1024)
                                  : ((cell == 1) ? (b12 + d * 1024)
                                                 : (b12 + (2 + d) * 1024));
    blds[cell][a] = bb[(a & 3) * 256 + u0 + (a >> 2)];
  }
  __syncthreads();

  unsigned* mycnt = (unsigned*)(wsb + OFF_CNT + (size_t)(bid & 7) * 64);

  for (unsigned tick = 0; tick < NTICK; ++tick) {
    const float* R = hb + ((tick + 1) & 1) * HBUF;  // produced last tick
    float* W = hb + (tick & 1) * HBUF;              // produced this tick
    const float4* Rf4 = (const float4*)R;

    const bool has0 = tick < 1024;
    const bool has1 = tick >= 1 && tick < 1025;
    const bool has2 = tick >= 2;

    float acc[8] = {0.f, 0.f, 0.f, 0.f, 0.f, 0.f, 0.f, 0.f};

    // ---- concurrent task phase: waves 0-3 L0, 4-9 L1, 10-15 L2 ----
    if (w < 4) {
      if (has0) {
        // L0: K4=80 (16 x cached + 64 rec h LLC), 20 k4 per wave
        if (w == 0) {
          runCached(acc, (const float4*)xT + (size_t)tick * 1024, 0, 0, 16,
                    wlds, lane);
          runLLC(acc, Rf4 + (size_t)d * 4096, 0, 16, 4, wlds, lane);
        } else {
          const int lo = 20 * w;  // task k4; h buffer k4 = lo-16
          runLLC(acc, Rf4 + (size_t)d * 4096, lo - 16, lo, 20, wlds, lane);
        }
      }
    } else if (w < 10) {
      if (has1) {
        // L1: K4=192 (128 = cells 0,1 ; 64 = rec cell 2+d), 32 k4 per wave
        const int wi = w - 4, lo = 32 * wi;
        if (wi < 4)
          runLLC(acc, Rf4, lo, lo, 32, wlds + 2560, lane);
        else
          runLLC(acc, Rf4 + (size_t)(2 + d) * 4096, lo - 128, lo, 32,
                 wlds + 2560, lane);
      }
    } else {
      if (has2) {
        // L2: K4=192 (128 = cells 2,3 ; 64 = rec cell 4+d), 32 k4 per wave
        const int wi = w - 10, lo = 32 * wi;
        if (wi < 4)
          runLLC(acc, Rf4 + (size_t)2 * 4096, lo, lo, 32, wlds + 8704, lane);
        else
          runLLC(acc, Rf4 + (size_t)(4 + d) * 4096, lo - 128, lo, 32,
                 wlds + 8704, lane);
      }
    }

    // partials -> LDS (absent tasks write zeros; never read)
    *(float4*)&red[w][lane][0] = make_float4(acc[0], acc[1], acc[2], acc[3]);
    *(float4*)&red[w][lane][4] = make_float4(acc[4], acc[5], acc[6], acc[7]);
    __syncthreads();

    // ---- fused epilogue: 192 threads = 3 cells x 64 batch ----
    if (tid < 192) {
      const int cell = tid >> 6, b = tid & 63;
      const bool present = (cell == 0) ? has0 : ((cell == 1) ? has1 : has2);
      if (present) {
        const int w0 = (cell == 0) ? 0 : ((cell == 1) ? 4 : 10);
        const int nw = (cell == 0) ? 4 : 6;
        float g0 = blds[cell][0], g1 = blds[cell][1], g2 = blds[cell][2],
              g3 = blds[cell][3], g4 = blds[cell][4], g5 = blds[cell][5],
              g6 = blds[cell][6], g7 = blds[cell][7];
        for (int ww = w0; ww < w0 + nw; ++ww) {
          const float4* rp = (const float4*)&red[ww][b][0];
          float4 s0 = rp[0], s1 = rp[1];
          g0 += s0.x; g1 += s0.y; g2 += s0.z; g3 += s0.w;
          g4 += s1.x; g5 += s1.y; g6 += s1.z; g7 += s1.w;
        }
        const float iv0 = sigf(g0), fv0 = sigf(g1), gv0 = tanhf_(g2),
                    ov0 = sigf(g3);
        const float iv1 = sigf(g4), fv1 = sigf(g5), gv1 = tanhf_(g6),
                    ov1 = sigf(g7);
        float c0 = fv0 * cst[cell][0][b] + iv0 * gv0;
        float c1 = fv1 * cst[cell][1][b] + iv1 * gv1;
        cst[cell][0][b] = c0;
        cst[cell][1][b] = c1;
        const float h0 = ov0 * tanhf_(c0), h1 = ov1 * tanhf_(c1);
        const int cellidx = (cell == 0) ? d : ((cell == 1) ? (2 + d) : (4 + d));
        float* hp =
            W + (size_t)cellidx * 16384 + (u0 >> 2) * 256 + b * 4 + (u0 & 3);
        llc_st_f2(hp, make_float2(h0, h1));  // no drain; shared drain below
        if (cell == 2 && d == 1) {
          // plain cached store: consumed by conv_argmax after kernel end
          *(float2*)(ys + (size_t)((int)tick - 2) * 16384 + b * 256 + u0) =
              make_float2(h0, h1);
        }
      }
    }
    // single drain for all h/ys stores, then block barrier
    asm volatile("s_waitcnt vmcnt(0)" ::: "memory");
    __syncthreads();

    // -------- grid barrier: pure relaxed LLC atomics, NO fences --------
    if (tid == 0) {
      unsigned old = __hip_atomic_fetch_add(mycnt, 1u, __ATOMIC_RELAXED,
                                            __HIP_MEMORY_SCOPE_AGENT);
      if (old == (tick + 1) * (NBLK / 8) - 1) {
        unsigned r = __hip_atomic_fetch_add(root, 1u, __ATOMIC_RELAXED,
                                            __HIP_MEMORY_SCOPE_AGENT);
        if (r == (tick + 1) * 8 - 1) {
          __hip_atomic_store(gen, tick + 1, __ATOMIC_RELAXED,
                             __HIP_MEMORY_SCOPE_AGENT);
        }
      }
      while (__hip_atomic_load(gen, __ATOMIC_RELAXED, __HIP_MEMORY_SCOPE_AGENT) <
             tick + 1) {
        __builtin_amdgcn_s_sleep(2);
      }
    }
    __syncthreads();
  }
}

// ---------------- conv(256->81) + argmax ----------------
__global__ __launch_bounds__(256) void conv_argmax(const float* __restrict__ yst,
                                                   const float* __restrict__ cw,
                                                   const float* __restrict__ cb,
                                                   int* __restrict__ out) {
  const int t = blockIdx.x;
  const int tid = threadIdx.x, lane = tid & 63, w = tid >> 6;
  const float* yrow = yst + (size_t)t * (B_ * H_) + lane * H_;
  float best = -3.4e38f;
  int bi = 0;
  for (int og = 0; og < 3; ++og) {
    float acc[8];
    int ov[8];
#pragma unroll
    for (int m = 0; m < 8; ++m) {
      int o = w + 32 * og + 4 * m;
      ov[m] = (o < 81) ? o : 80;
      acc[m] = (o < 81) ? cb[o] : -3.4e38f;
    }
    for (int uu = 0; uu < H_; uu += 4) {
      float4 y4 = *(const float4*)(yrow + uu);
#pragma unroll
      for (int m = 0; m < 8; ++m) {
        const float* wr = cw + ov[m] * H_ + uu;
        acc[m] += wr[0] * y4.x + wr[1] * y4.y + wr[2] * y4.z + wr[3] * y4.w;
      }
    }
#pragma unroll
    for (int m = 0; m < 8; ++m) {
      int o = w + 32 * og + 4 * m;
      if (o < 81 && acc[m] > best) {
        best = acc[m];
        bi = o;
      }
    }
  }
  __shared__ float sv[4][64];
  __shared__ int si[4][64];
  sv[w][lane] = best;
  si[w][lane] = bi;
  __syncthreads();
  if (tid < 64) {
    float bv = sv[0][tid];
    int bo = si[0][tid];
#pragma unroll
    for (int ww = 1; ww < 4; ++ww) {
      float v = sv[ww][tid];
      int o = si[ww][tid];
      if (v > bv || (v == bv && o < bo)) {
        bv = v;
        bo = o;
      }
    }
    out[tid * T_ + t] = bo;
  }
}

extern "C" void kernel_launch(void* const* d_in, const int* in_sizes, int n_in,
                              void* d_out, int out_size, void* d_ws,
                              size_t ws_size, hipStream_t stream) {
  const float* x = (const float*)d_in[0];
  const float* Wih0 = (const float*)d_in[1];
  const float* Whh0 = (const float*)d_in[2];
  const float* b0 = (const float*)d_in[3];
  const float* Wih12 = (const float*)d_in[4];
  const float* Whh12 = (const float*)d_in[5];
  const float* b12 = (const float*)d_in[6];
  const float* cw = (const float*)d_in[7];
  const float* cb = (const float*)d_in[8];
  int* out = (int*)d_out;
  char* wsb = (char*)d_ws;

  // zero flags + h ring (ws is re-poisoned 0xAA before every launch)
  hipMemsetAsync(wsb, 0, OFF_H + 786432, stream);
  transpose_x<<<dim3(16, 64, 1), dim3(64, 1, 1), 0, stream>>>(
      x, (float*)(wsb + OFF_XT));
  lstm_persistent<<<dim3(NBLK, 1, 1), dim3(NTHR, 1, 1), 0, stream>>>(
      Wih0, Whh0, b0, Wih12, Whh12, b12, wsb);
  conv_argmax<<<dim3(T_, 1, 1), dim3(256, 1, 1), 0, stream>>>(
      (const float*)(wsb + OFF_YS), cw, cb, out);
}